// Round 4
// baseline (131.652 us; speedup 1.0000x reference)
//
#include <hip/hip_runtime.h>

// NCC loss, win=9, (1,1,160,192,224) fp32 -> scalar. Fully fused, round 13.
// R12 post-mortem: 1 barrier/slice gained only 6% -> stall is the STRAGGLER
// wave, not barrier count. Wave 2 did H+W+F (~620 issue-cyc) vs ~230 for
// waves 0/1; 3 of 4 waves idled at each barrier.
// R13: roles wave-disjoint + SH stage deleted:
//   - H is now an IN-PLACE PREFIX SUM over SW columns (17 rows: P[0]=0,
//     P[r]=P[r-1]+W-sum row r). F computes its 9-row H-window as
//     P[ty+9]-P[ty]: 2 LDS reads/ch. SH (and its write+read) is gone.
//   - W -> tids 0-127 (waves 0,1); H -> tids 128-255 (waves 2,3); F -> all.
//     Critical wave ~240 issue-cyc/phase (was ~620).
//   - SW triple-buffered (mod 3; 36 iters = 12x3 so ph%3 is static after
//     unroll). Phase j: F reads buf[j%3], H rewrites buf[(j+1)%3], W writes
//     buf[(j+2)%3] -- disjoint in-phase; each producer->consumer pair crosses
//     exactly one barrier. One LDS-only barrier per slice (vmcnt spans it).
// LDS 36.7 KB -> 4 blocks/CU unchanged. DCH=28, 1008 blocks (R10/R12 best).

#define DD 160
#define HH 192
#define WW 224
#define W4 56                 // WW/4
#define SLICE (HH * WW)
#define S4 (SLICE / 4)
#define NVOX (DD * SLICE)
#define TW 32
#define TH 8
#define DCH 28                // grid.z = 6 -> 1008 blocks
#define ITERS (DCH + 8)       // 36 = 4 * 9 (phase-static ring, 12 * 3 buffers)
#define NTHR 256
#define SW_RS 36              // row stride (dwords); b128-aligned, 0-conflict
#define SW_CS (17 * SW_RS)    // 612: 17 rows = 16 data rows + zero prefix row
#define EPS 1e-5f
#define INV_WSUM (1.0f / 729.0f)

// Barrier that orders LDS only: s_waitcnt imm 0xC07F = lgkmcnt(0), vmcnt(63),
// expcnt(7) -> in-flight GLOBAL loads stay in flight across the barrier.
__device__ __forceinline__ void bar_lds_only() {
    __asm__ volatile("" ::: "memory");
    __builtin_amdgcn_s_waitcnt(0xC07F);
    __builtin_amdgcn_s_barrier();
    __asm__ volatile("" ::: "memory");
}

__global__ __launch_bounds__(NTHR, 4) void ncc_fused(const float* __restrict__ I,
                                                     const float* __restrict__ J,
                                                     float* __restrict__ out) {
    __shared__ float SW0[5 * SW_CS], SW1[5 * SW_CS], SW2[5 * SW_CS]; // 12.24KB ea
    __shared__ float wred[NTHR / 64];

    const int tid = threadIdx.x;
    const int tx = tid & 31, ty = tid >> 5;    // F mapping: 32 x 8
    const int wlo = blockIdx.x * TW;
    const int hlo = blockIdx.y * TH;
    const int dlo = blockIdx.z * DCH;

    // W-group (tid < 128): 16 rows x 8 f4-col groups
    const int wr = tid >> 3, wc = tid & 7;
    const int gh = hlo - 4 + wr;
    const bool hok = (gh >= 0) && (gh < HH);
    const int gf0 = (wlo >> 2) - 1 + wc;

    // H-group (tid >= 128): 4 channels x 32 cols; ht<32 also does ch4
    const int ht = tid - 128;
    const int hcol = ht & 31, hch = ht >> 5;

    const float4* Iv = (const float4*)I;
    const float4* Jv = (const float4*)J;

    // prefetch registers: one slice-row of raw I/J (12 floats each)
    float pfa[12], pfb[12];

    auto w_load = [&](int z) {   // fill pfa/pfb for slice z (zeros if OOB)
        const bool zok = (z >= 0) && (z < DD) && hok;
        const int rowb = z * S4 + gh * W4;
        #pragma unroll
        for (int k = 0; k < 3; ++k) {
            const int f = gf0 + k;
            float4 a = make_float4(0.f, 0.f, 0.f, 0.f);
            float4 b = make_float4(0.f, 0.f, 0.f, 0.f);
            if (zok && f >= 0 && f < W4) { a = Iv[rowb + f]; b = Jv[rowb + f]; }
            pfa[4*k] = a.x; pfa[4*k+1] = a.y; pfa[4*k+2] = a.z; pfa[4*k+3] = a.w;
            pfb[4*k] = b.x; pfb[4*k+1] = b.y; pfb[4*k+2] = b.z; pfb[4*k+3] = b.w;
        }
    };

    auto w_compute = [&](float* dst) {   // slide 9-tap W-sums -> dst rows 1..16
        float* wp = dst + (wr + 1) * SW_RS + 4 * wc;
        #pragma unroll
        for (int ch = 0; ch < 5; ++ch) {
            float v[12];
            #pragma unroll
            for (int k = 0; k < 12; ++k)
                v[k] = (ch == 0) ? pfa[k]
                     : (ch == 1) ? pfb[k]
                     : (ch == 2) ? pfa[k] * pfa[k]
                     : (ch == 3) ? pfb[k] * pfb[k]
                     :             pfa[k] * pfb[k];
            float s = v[0];
            #pragma unroll
            for (int k = 1; k < 9; ++k) s += v[k];
            float4 o;
            o.x = s;
            s += v[9]  - v[0]; o.y = s;
            s += v[10] - v[1]; o.z = s;
            s += v[11] - v[2]; o.w = s;
            *(float4*)(wp + ch * SW_CS) = o;   // b128, 16B-aligned
        }
    };

    auto h_one = [&](float* buf, int col, int ch) {  // in-place column prefix
        float* base = buf + ch * SW_CS + col;
        float v[16];
        #pragma unroll
        for (int r = 0; r < 16; r += 2) {            // pairs -> ds_read2-able
            const float* pr = base + (r + 1) * SW_RS;
            v[r]     = pr[0];
            v[r + 1] = pr[SW_RS];
        }
        base[0] = 0.f;
        float run = 0.f;
        #pragma unroll
        for (int r = 0; r < 16; ++r) {
            run += v[r];
            base[(r + 1) * SW_RS] = run;
        }
    };

    auto h_phase = [&](float* buf) {
        h_one(buf, hcol, hch);
        if (ht < 32) h_one(buf, hcol, 4);            // ch4 double-duty
    };

    auto bsel = [&](int m) -> float* {               // m is compile-time const
        return (m == 0) ? SW0 : (m == 1) ? SW1 : SW2;
    };

    float q0[9], q1[9], q2[9], q3[9], q4[9];
    #pragma unroll
    for (int k = 0; k < 9; ++k) { q0[k]=0.f; q1[k]=0.f; q2[k]=0.f; q3[k]=0.f; q4[k]=0.f; }
    float r0=0.f, r1=0.f, r2=0.f, r3=0.f, r4=0.f;
    float acc = 0.f;

    // ---- prologue ----
    const int z0 = dlo - 4;
    if (tid < 128) {                     // pro0: W(0)->SW0, prefetch slice 1
        w_load(z0);
        if (z0 >= 0) w_compute(SW0);     // z0 < DD always (dlo <= 140)
        w_load(z0 + 1);
    }
    bar_lds_only();
    // pro1: H(0) on SW0; W(1)->SW1; prefetch slice 2
    if (tid >= 128 && z0 >= 0) h_phase(SW0);
    if (tid < 128) {
        const int z1 = z0 + 1;
        if (z1 >= 0 && z1 < DD) w_compute(SW1);
        w_load(z0 + 2);
    }

    // ---- main: 36 phases, ONE barrier each ----
    #pragma unroll 1
    for (int g = 0; g < 4; ++g) {
        #pragma unroll
        for (int ph = 0; ph < 9; ++ph) {
            const int j = 9 * g + ph;
            const int z = dlo - 4 + j;               // slice consumed by F(j)
            bar_lds_only();   // orders H(j)->F(j), W(j+1)->H(j+1), F done w/ buf

            // F(j): 2 reads/ch off the prefix columns
            const bool val = (z >= 0) && (z < DD);   // block-uniform
            float w0=0.f, w1=0.f, w2=0.f, w3=0.f, w4=0.f;
            if (val) {
                const float* pb = bsel(ph % 3) + ty * SW_RS + tx;
                w0 = pb[9*SW_RS]              - pb[0];
                w1 = pb[SW_CS   + 9*SW_RS]    - pb[SW_CS];
                w2 = pb[2*SW_CS + 9*SW_RS]    - pb[2*SW_CS];
                w3 = pb[3*SW_CS + 9*SW_RS]    - pb[3*SW_CS];
                w4 = pb[4*SW_CS + 9*SW_RS]    - pb[4*SW_CS];
            }

            // H(j+1): in-place prefix on buf[(j+1)%3]
            if (j < ITERS - 1 && tid >= 128) {
                const int zh = z + 1;
                if (zh >= 0 && zh < DD) h_phase(bsel((ph + 1) % 3));
            }

            // W(j+2): pf regs -> buf[(j+2)%3]; refill pf
            if (j < ITERS - 2 && tid < 128) {
                const int zw = z + 2;
                if (zw >= 0 && zw < DD) w_compute(bsel((ph + 2) % 3));
                w_load(z + 3);
            }

            // ring update + cc
            r0 += w0 - q0[ph]; q0[ph] = w0;
            r1 += w1 - q1[ph]; q1[ph] = w1;
            r2 += w2 - q2[ph]; q2[ph] = w2;
            r3 += w3 - q3[ph]; q3[ph] = w3;
            r4 += w4 - q4[ph]; q4[ph] = w4;

            if (j >= 8 && (dlo + j - 8) < DD) {   // last chunk overhangs to 167
                float cross = r4 - r0 * r1 * INV_WSUM;
                float iv    = r2 - r0 * r0 * INV_WSUM;
                float jv    = r3 - r1 * r1 * INV_WSUM;
                acc += cross * cross * __builtin_amdgcn_rcpf(iv * jv + EPS);
            }
        }
    }

    // ---- block reduction -> one atomic (cold path: full __syncthreads ok) ----
    #pragma unroll
    for (int off = 32; off > 0; off >>= 1) acc += __shfl_down(acc, off, 64);
    if ((tid & 63) == 0) wred[tid >> 6] = acc;
    __syncthreads();
    if (tid == 0) {
        float t = 0.f;
        #pragma unroll
        for (int k = 0; k < NTHR / 64; ++k) t += wred[k];
        atomicAdd(out, t * (-1.0f / (float)NVOX));
    }
}

extern "C" void kernel_launch(void* const* d_in, const int* in_sizes, int n_in,
                              void* d_out, int out_size, void* d_ws, size_t ws_size,
                              hipStream_t stream) {
    const float* I = (const float*)d_in[0];
    const float* J = (const float*)d_in[1];
    float* out = (float*)d_out;

    hipMemsetAsync(d_out, 0, sizeof(float), stream);  // harness re-poisons d_out

    dim3 blk(NTHR, 1, 1);
    dim3 grd(WW / TW, HH / TH, (DD + DCH - 1) / DCH); // 7 x 24 x 6 = 1008 blocks
    ncc_fused<<<grd, blk, 0, stream>>>(I, J, out);
}